// Round 12
// baseline (368.968 us; speedup 1.0000x reference)
//
#include <hip/hip_runtime.h>
#include <hip/hip_bf16.h>
#include <cstdint>

#define DEVI __device__ __forceinline__

typedef __attribute__((ext_vector_type(8))) short bf16x8;
typedef __attribute__((ext_vector_type(4))) float f32x4;

DEVI float bf2f(unsigned short u) {
    union { unsigned int i; float f; } v; v.i = ((unsigned int)u) << 16; return v.f;
}
DEVI float ldf(const void* p, long long i, int f32) {
    return f32 ? ((const float*)p)[i] : bf2f(((const unsigned short*)p)[i]);
}
DEVI unsigned short f2bfu(float x) {
    __hip_bfloat16 h = __float2bfloat16(x);
    return *reinterpret_cast<unsigned short*>(&h);
}
DEVI short f2bf(float x) { return (short)f2bfu(x); }
DEVI float eluf(float x) { return x > 0.f ? x : __expf(x) - 1.f; }

// ---- flag detection: flags[0]=edge_index is int64, flags[1]=floats are fp32
__global__ __launch_bounds__(64) void detect_k(
    const int* __restrict__ eidx32, const unsigned int* __restrict__ wbits,
    int* __restrict__ flags)
{
    int t = threadIdx.x;
    int odd = eidx32[2 * t + 1];
    unsigned long long bz = __ballot(odd == 0);
    unsigned int w = wbits[t];
    unsigned int ex = (w >> 23) & 0xFF;
    unsigned long long bf = __ballot(ex >= 100 && ex <= 130);
    if (t == 0) {
        flags[0] = (bz == ~0ULL) ? 1 : 0;
        flags[1] = (__popcll(bf) >= 48) ? 1 : 0;
    }
}

// -------------- Kernel 1: node pathway -> qkv_bf16[M,64] --------------------
__global__ __launch_bounds__(256) void node_qkv_k(
    const int* __restrict__ flags,
    const void* __restrict__ evec,
    const void* __restrict__ W1, const void* __restrict__ b1,
    const void* __restrict__ W2, const void* __restrict__ b2,
    const void* __restrict__ W,  const void* __restrict__ b,
    unsigned short* __restrict__ qkvb, int M_)
{
    __shared__ float sW[1024], sW2[64], sb[64], sb2[16], sW1[4], sb1[4];
    int t = threadIdx.x;
    int f32 = flags[1];
    for (int i = t; i < 1024; i += 256) sW[i] = ldf(W, i, f32);
    if (t < 64) { sW2[t] = ldf(W2, t, f32); sb[t] = ldf(b, t, f32); }
    if (t < 16) sb2[t] = ldf(b2, t, f32);
    if (t < 4)  { sW1[t] = ldf(W1, t, f32); sb1[t] = ldf(b1, t, f32); }
    __syncthreads();

    int m = blockIdx.x * 256 + t;
    if (m >= M_) return;

    float x = ldf(evec, m, f32);
    float h1[4];
    #pragma unroll
    for (int j = 0; j < 4; ++j) h1[j] = eluf(fmaf(x, sW1[j], sb1[j]));
    float h2[16];
    #pragma unroll
    for (int k = 0; k < 16; ++k) h2[k] = sb2[k];
    #pragma unroll
    for (int j = 0; j < 4; ++j)
        #pragma unroll
        for (int k = 0; k < 16; ++k) h2[k] = fmaf(h1[j], sW2[j*16 + k], h2[k]);

    uint4* op = (uint4*)(qkvb + (size_t)m * 64);
    for (int g = 0; g < 8; ++g) {
        float v[8];
        #pragma unroll
        for (int j = 0; j < 8; ++j) {
            int c = g * 8 + j;
            float a = sb[c];
            #pragma unroll
            for (int k = 0; k < 16; ++k) a = fmaf(h2[k], sW[k*64 + c], a);
            v[j] = a;
        }
        uint4 pk;
        pk.x = (unsigned)f2bfu(v[0]) | ((unsigned)f2bfu(v[1]) << 16);
        pk.y = (unsigned)f2bfu(v[2]) | ((unsigned)f2bfu(v[3]) << 16);
        pk.z = (unsigned)f2bfu(v[4]) | ((unsigned)f2bfu(v[5]) << 16);
        pk.w = (unsigned)f2bfu(v[6]) | ((unsigned)f2bfu(v[7]) << 16);
        op[g] = pk;
    }
}

// --- Kernel 2: histogram of dst (4 edges/thread) + per-edge rank output -----
__global__ __launch_bounds__(256) void hist_k(
    const int* __restrict__ flags, const int* __restrict__ eidx32,
    int* __restrict__ counts, int* __restrict__ rank, int NE_)
{
    int e0 = (blockIdx.x * 256 + threadIdx.x) * 4;
    if (e0 >= NE_) return;
    int i64 = flags[0];
    if (e0 + 3 < NE_) {
        int d[4];
        if (i64) {
            long long w = 2LL * (NE_ + (long long)e0);
            int4 a = *(const int4*)(eidx32 + w);
            int4 b = *(const int4*)(eidx32 + w + 4);
            d[0] = a.x; d[1] = a.z; d[2] = b.x; d[3] = b.z;
        } else {
            #pragma unroll
            for (int i = 0; i < 4; ++i) d[i] = eidx32[(long long)NE_ + e0 + i];
        }
        int r[4];
        #pragma unroll
        for (int i = 0; i < 4; ++i) r[i] = atomicAdd(&counts[d[i]], 1);
        *(int4*)(rank + e0) = make_int4(r[0], r[1], r[2], r[3]);
    } else {
        for (int e = e0; e < NE_; ++e) {
            int dst = i64 ? eidx32[2LL * (NE_ + (long long)e)]
                          : eidx32[(long long)NE_ + e];
            rank[e] = atomicAdd(&counts[dst], 1);
        }
    }
}

// ---------------- Kernel 3a: per-1024-tile block sums ----------------
__global__ __launch_bounds__(256) void scan_a_k(
    const int* __restrict__ counts, int* __restrict__ bsum, int M_)
{
    __shared__ int s[256];
    int t = threadIdx.x;
    int g4 = blockIdx.x * 256 + t;
    int i0 = g4 * 4;
    int v = 0;
    if (i0 + 3 < M_) {
        int4 c = ((const int4*)counts)[g4];
        v = c.x + c.y + c.z + c.w;
    } else {
        for (int k = 0; k < 4 && i0 + k < M_; ++k) v += counts[i0 + k];
    }
    s[t] = v; __syncthreads();
    for (int off = 128; off > 0; off >>= 1) {
        if (t < off) s[t] += s[t + off];
        __syncthreads();
    }
    if (t == 0) bsum[blockIdx.x] = s[0];
}

// ---------------- Kernel 3b: scan block sums (nb <= 256) ----------------
__global__ __launch_bounds__(256) void scan_b_k(
    const int* __restrict__ bsum, int* __restrict__ bexcl, int nb,
    int* __restrict__ offsets, int M_, int NE_)
{
    __shared__ int s[256];
    int t = threadIdx.x;
    int mine = (t < nb) ? bsum[t] : 0;
    s[t] = mine; __syncthreads();
    for (int off = 1; off < 256; off <<= 1) {
        int v = (t >= off) ? s[t - off] : 0;
        __syncthreads();
        s[t] += v;
        __syncthreads();
    }
    if (t < nb) bexcl[t] = s[t] - mine;
    if (t == 0) offsets[M_] = NE_;
}

// ---------------- Kernel 3c: final offsets ----------------
__global__ __launch_bounds__(256) void scan_c_k(
    const int* __restrict__ counts, const int* __restrict__ bexcl,
    int* __restrict__ offsets, int M_)
{
    __shared__ int s[256];
    int t = threadIdx.x;
    int g4 = blockIdx.x * 256 + t;
    int i0 = g4 * 4;
    int c0 = 0, c1 = 0, c2 = 0, c3 = 0;
    if (i0 + 3 < M_) {
        int4 c = ((const int4*)counts)[g4];
        c0 = c.x; c1 = c.y; c2 = c.z; c3 = c.w;
    } else {
        if (i0 + 0 < M_) c0 = counts[i0 + 0];
        if (i0 + 1 < M_) c1 = counts[i0 + 1];
        if (i0 + 2 < M_) c2 = counts[i0 + 2];
        if (i0 + 3 < M_) c3 = counts[i0 + 3];
    }
    int tsum = c0 + c1 + c2 + c3;
    s[t] = tsum; __syncthreads();
    for (int off = 1; off < 256; off <<= 1) {
        int v = (t >= off) ? s[t - off] : 0;
        __syncthreads();
        s[t] += v;
        __syncthreads();
    }
    int run = bexcl[blockIdx.x] + s[t] - tsum;
    if (i0 + 0 < M_) { offsets[i0+0] = run; run += c0; }
    if (i0 + 1 < M_) { offsets[i0+1] = run; run += c1; }
    if (i0 + 2 < M_) { offsets[i0+2] = run; run += c2; }
    if (i0 + 3 < M_) { offsets[i0+3] = run; run += c3; }
}

// --- Kernel 4: scatter records {src, dst, efeat(4xbf16)}; atomic-free -------
__global__ __launch_bounds__(256) void scatter_k(
    const int* __restrict__ flags, const int* __restrict__ eidx32,
    const void* __restrict__ efeat,
    const int* __restrict__ offsets, const int* __restrict__ rank,
    int4* __restrict__ sorted, int NE_)
{
    int e = blockIdx.x * 256 + threadIdx.x;
    if (e >= NE_) return;
    int i64 = flags[0];
    int f32 = flags[1];
    int src, dst;
    if (i64) { src = eidx32[2LL * e]; dst = eidx32[2LL * (NE_ + (long long)e)]; }
    else     { src = eidx32[e];       dst = eidx32[(long long)NE_ + e]; }

    unsigned int ef01, ef23;
    if (f32) {
        const float4 f = ((const float4*)efeat)[e];
        ef01 = (unsigned)f2bfu(f.x) | ((unsigned)f2bfu(f.y) << 16);
        ef23 = (unsigned)f2bfu(f.z) | ((unsigned)f2bfu(f.w) << 16);
    } else {
        const uint2 u = ((const uint2*)efeat)[e];
        ef01 = u.x; ef23 = u.y;
    }

    int pos = offsets[dst] + rank[e];     // no atomic: rank captured in hist_k
    sorted[pos] = make_int4(src, dst, (int)ef01, (int)ef23);
}

// ----- Kernel 5: scores via MFMA + LDS transpose (16 j per wave-tile) -------
// grid-strided; next-tile record prefetched to hide the sorted[] fetch
__global__ __launch_bounds__(256) void score_k(
    const int* __restrict__ flags, const int4* __restrict__ sorted,
    const void* __restrict__ W2, const void* __restrict__ b2,
    const void* __restrict__ W,  const void* __restrict__ b,
    const unsigned short* __restrict__ qkvb, float* __restrict__ score, int NE_)
{
    __shared__ float sW2[64], sb2[16];
    __shared__ float sE[4][16 * 68];
    int t = threadIdx.x;
    int f32 = flags[1];
    if (t < 64) sW2[t] = ldf(W2, t, f32);
    if (t < 16) sb2[t] = ldf(b2, t, f32);
    __syncthreads();

    int wv   = t >> 6;
    int lane = t & 63;
    int col  = lane & 15;
    int quad = lane >> 4;
    float* myE = &sE[wv][0];

    bf16x8 bfrag[4];
    float  bb[4];
    #pragma unroll
    for (int h = 0; h < 4; ++h) {
        #pragma unroll
        for (int jj = 0; jj < 8; ++jj) {
            int k = quad * 8 + jj;
            float wv_ = (k < 16) ? ldf(W, k * 64 + h * 16 + col, f32) : 0.f;
            bfrag[h][jj] = f2bf(wv_);
        }
        bb[h] = ldf(b, h * 16 + col, f32);
    }

    int j2 = lane >> 2, h2 = lane & 3;

    long long tiles = ((long long)NE_ + 15) >> 4;
    long long wid   = (long long)blockIdx.x * 4 + wv;
    long long nw    = (long long)gridDim.x * 4;

    long long tile = wid;
    int4 rec = make_int4(0, 0, 0, 0);
    if (tile < tiles) {
        int jA = (int)(tile << 4) + col;
        if (jA < NE_) rec = sorted[jA];
    }

    while (tile < tiles) {
        // prefetch next tile's record before this tile's heavy work
        long long tnext = tile + nw;
        int4 recn = make_int4(0, 0, 0, 0);
        if (tnext < tiles) {
            int jB = (int)(tnext << 4) + col;
            if (jB < NE_) recn = sorted[jB];
        }

        int base = (int)(tile << 4);
        float ef0 = bf2f((unsigned short)((unsigned)rec.z & 0xffff));
        float ef1 = bf2f((unsigned short)((unsigned)rec.z >> 16));
        float ef2 = bf2f((unsigned short)((unsigned)rec.w & 0xffff));
        float ef3 = bf2f((unsigned short)((unsigned)rec.w >> 16));

        bf16x8 afrag;
        #pragma unroll
        for (int jj = 0; jj < 8; ++jj) {
            int k = quad * 8 + jj;
            float v = 0.f;
            if (k < 16) {
                v = eluf(fmaf(ef0, sW2[k],
                        fmaf(ef1, sW2[16 + k],
                        fmaf(ef2, sW2[32 + k],
                        fmaf(ef3, sW2[48 + k], sb2[k])))));
            }
            afrag[jj] = f2bf(v);
        }

        f32x4 acc[4];
        #pragma unroll
        for (int h = 0; h < 4; ++h) {
            acc[h] = (f32x4){0.f, 0.f, 0.f, 0.f};
            acc[h] = __builtin_amdgcn_mfma_f32_16x16x32_bf16(afrag, bfrag[h], acc[h], 0, 0, 0);
        }

        #pragma unroll
        for (int h = 0; h < 4; ++h)
            #pragma unroll
            for (int r = 0; r < 4; ++r)
                myE[(quad * 4 + r) * 68 + h * 16 + col] = acc[h][r] + bb[h];

        asm volatile("s_waitcnt lgkmcnt(0)" ::: "memory");

        int srcj = __shfl(rec.x, j2, 64);
        int dstj = __shfl(rec.y, j2, 64);

        const uint4* sp = (const uint4*)(qkvb + (size_t)srcj * 64 + h2 * 16);
        const uint4* dp = (const uint4*)(qkvb + (size_t)dstj * 64 + h2 * 16);
        uint4 sA = sp[0], sB = sp[1], dA = dp[0], dB = dp[1];

        const float4* ep = (const float4*)(myE + j2 * 68 + h2 * 16);
        float4 e0 = ep[0], e1 = ep[1], e2 = ep[2], e3 = ep[3];
        float E[16] = {e0.x,e0.y,e0.z,e0.w, e1.x,e1.y,e1.z,e1.w,
                       e2.x,e2.y,e2.z,e2.w, e3.x,e3.y,e3.z,e3.w};

        unsigned int su[8] = {sA.x,sA.y,sA.z,sA.w, sB.x,sB.y,sB.z,sB.w};
        unsigned int du[8] = {dA.x,dA.y,dA.z,dA.w, dB.x,dB.y,dB.z,dB.w};

        float sc = 0.f;
        #pragma unroll
        for (int i = 0; i < 8; ++i) {
            float s0 = bf2f((unsigned short)(su[i] & 0xffff));
            float s1 = bf2f((unsigned short)(su[i] >> 16));
            float d0 = bf2f((unsigned short)(du[i] & 0xffff));
            float d1 = bf2f((unsigned short)(du[i] >> 16));
            sc = fmaf(s0 * d0, E[2*i],   sc);
            sc = fmaf(s1 * d1, E[2*i+1], sc);
        }
        sc *= 0.25f;
        sc = fminf(fmaxf(sc, -5.f), 5.f);
        float s = __expf(sc);

        int jW = base + j2;
        if (jW < NE_) score[(size_t)jW * 4 + h2] = s;

        rec = recn;
        tile = tnext;
    }
}

// --- Kernel 6: per-(dst,head) accumulate (4-deep pipeline) + output MLP -----
__global__ __launch_bounds__(256) void accum_out_k(
    const int* __restrict__ flags,
    const int* __restrict__ offsets, const int4* __restrict__ sorted,
    const float* __restrict__ score, const unsigned short* __restrict__ qkvb,
    const void* __restrict__ Wout, const void* __restrict__ bout,
    const void* __restrict__ Wout1, const void* __restrict__ bout1,
    void* __restrict__ out, int M_)
{
    __shared__ float sWo[1024], sbo[16], sWo1[16];
    __shared__ float sbo1;
    int t = threadIdx.x;
    int f32 = flags[1];
    for (int i = t; i < 1024; i += 256) sWo[i] = ldf(Wout, i, f32);
    if (t < 16) { sbo[t] = ldf(bout, t, f32); sWo1[t] = ldf(Wout1, t, f32); }
    if (t == 0) sbo1 = ldf(bout1, 0, f32);
    __syncthreads();

    int gid = blockIdx.x * 256 + t;
    int m = gid >> 2;
    if (m >= M_) return;
    int h  = gid & 3;
    int hb = h * 16;

    int beg = offsets[m], end = offsets[m + 1];

    float acc[16];
    #pragma unroll
    for (int d = 0; d < 16; ++d) acc[d] = 0.f;
    float z = 0.f;

    int j = beg;
    // 4-edge unrolled: batch all loads first (8 row-loads in flight), then FMA
    for (; j + 4 <= end; j += 4) {
        int s4[4];
        float sc4[4];
        #pragma unroll
        for (int u = 0; u < 4; ++u) {
            s4[u]  = sorted[j + u].x;
            sc4[u] = score[(size_t)(j + u) * 4 + h];
        }
        uint4 qa[4], qb[4];
        #pragma unroll
        for (int u = 0; u < 4; ++u) {
            const uint4* p = (const uint4*)(qkvb + (size_t)s4[u] * 64 + hb);
            qa[u] = p[0]; qb[u] = p[1];
        }
        #pragma unroll
        for (int u = 0; u < 4; ++u) {
            float s = sc4[u];
            z += s;
            unsigned int q[8] = {qa[u].x,qa[u].y,qa[u].z,qa[u].w,
                                 qb[u].x,qb[u].y,qb[u].z,qb[u].w};
            #pragma unroll
            for (int i = 0; i < 8; ++i) {
                acc[2*i]   = fmaf(bf2f((unsigned short)(q[i] & 0xffff)), s, acc[2*i]);
                acc[2*i+1] = fmaf(bf2f((unsigned short)(q[i] >> 16)),    s, acc[2*i+1]);
            }
        }
    }
    for (; j < end; ++j) {
        int s0 = sorted[j].x;
        float sc0 = score[(size_t)j * 4 + h];
        const uint4* p0 = (const uint4*)(qkvb + (size_t)s0 * 64 + hb);
        uint4 a0 = p0[0], a1 = p0[1];
        z += sc0;
        unsigned int q0[8] = {a0.x,a0.y,a0.z,a0.w, a1.x,a1.y,a1.z,a1.w};
        #pragma unroll
        for (int i = 0; i < 8; ++i) {
            acc[2*i]   = fmaf(bf2f((unsigned short)(q0[i] & 0xffff)), sc0, acc[2*i]);
            acc[2*i+1] = fmaf(bf2f((unsigned short)(q0[i] >> 16)),    sc0, acc[2*i+1]);
        }
    }

    float zinv = 1.f / (z + 1e-6f);

    float p[16];
    #pragma unroll
    for (int jj = 0; jj < 16; ++jj) p[jj] = 0.f;
    #pragma unroll
    for (int d = 0; d < 16; ++d) {
        float hv = acc[d] * zinv;
        #pragma unroll
        for (int jj = 0; jj < 16; ++jj) p[jj] = fmaf(hv, sWo[(hb + d) * 16 + jj], p[jj]);
    }
    #pragma unroll
    for (int jj = 0; jj < 16; ++jj) {
        p[jj] += __shfl_xor(p[jj], 1, 64);
        p[jj] += __shfl_xor(p[jj], 2, 64);
    }
    if (h == 0) {
        float o = sbo1;
        #pragma unroll
        for (int jj = 0; jj < 16; ++jj) o = fmaf(eluf(p[jj] + sbo[jj]), sWo1[jj], o);
        if (f32) ((float*)out)[m] = o;
        else     ((__hip_bfloat16*)out)[m] = __float2bfloat16(o);
    }
}

extern "C" void kernel_launch(void* const* d_in, const int* in_sizes, int n_in,
                              void* d_out, int out_size, void* d_ws, size_t ws_size,
                              hipStream_t stream)
{
    const int*  eidx  = (const int*)d_in[1];
    const void* efeat = d_in[2];
    const void* evec  = d_in[3];
    const void* W1 = d_in[4],  *b1 = d_in[5];
    const void* W2 = d_in[6],  *b2 = d_in[7];
    const void* W  = d_in[8],  *b  = d_in[9];
    const void* Wout = d_in[10], *bout = d_in[11];
    const void* Wout1 = d_in[12], *bout1 = d_in[13];

    const int M_  = in_sizes[3];       // 150000
    const int NE_ = in_sizes[1] / 2;   // 1500000
    const int nb  = (M_ + 1023) / 1024;

    // workspace layout (16B aligned); ~75 MB (<79.2 MB proven available)
    char* wp = (char*)d_ws;
    int*            flags   = (int*)wp;                 wp += 16;
    unsigned short* qkvb    = (unsigned short*)wp;      wp += (size_t)M_ * 64 * 2;
    int*            counts  = (int*)wp;                 wp += (size_t)M_ * 4;
    int*            bsum    = (int*)wp;                 wp += 2048 * 4;
    int*            bexcl   = (int*)wp;                 wp += 2048 * 4;
    int*            offsets = (int*)wp;                 wp += ((size_t)M_ + 4) * 4;
    int*            rank    = (int*)wp;                 wp += (size_t)NE_ * 4;
    wp = (char*)(((uintptr_t)wp + 15) & ~(uintptr_t)15);
    int4*           sorted  = (int4*)wp;                wp += (size_t)NE_ * 16;
    float*          scoreB  = (float*)wp;               // NE*4 fp32 = 24 MB

    detect_k<<<1, 64, 0, stream>>>(eidx, (const unsigned int*)W, flags);
    (void)hipMemsetAsync(counts, 0, (size_t)M_ * 4, stream);

    node_qkv_k<<<(M_ + 255) / 256, 256, 0, stream>>>(
        flags, evec, W1, b1, W2, b2, W, b, qkvb, M_);

    int q4 = (NE_ + 3) / 4;
    hist_k<<<(q4 + 255) / 256, 256, 0, stream>>>(flags, eidx, counts, rank, NE_);
    scan_a_k<<<nb, 256, 0, stream>>>(counts, bsum, M_);
    scan_b_k<<<1, 256, 0, stream>>>(bsum, bexcl, nb, offsets, M_, NE_);
    scan_c_k<<<nb, 256, 0, stream>>>(counts, bexcl, offsets, M_);
    scatter_k<<<(NE_ + 255) / 256, 256, 0, stream>>>(
        flags, eidx, efeat, offsets, rank, sorted, NE_);

    long long tiles = ((long long)NE_ + 15) / 16;
    int sblocks = (int)((tiles + 3) / 4);
    if (sblocks > 12288) sblocks = 12288;
    score_k<<<sblocks, 256, 0, stream>>>(
        flags, sorted, W2, b2, W, b, qkvb, scoreB, NE_);

    long long tot = (long long)M_ * 4;
    accum_out_k<<<(int)((tot + 255) / 256), 256, 0, stream>>>(
        flags, offsets, sorted, scoreB, qkvb,
        Wout, bout, Wout1, bout1, d_out, M_);
}

// Round 13
// 367.823 us; speedup vs baseline: 1.0031x; 1.0031x over previous
//
#include <hip/hip_runtime.h>
#include <hip/hip_bf16.h>
#include <cstdint>

#define DEVI __device__ __forceinline__

typedef __attribute__((ext_vector_type(8))) short bf16x8;
typedef __attribute__((ext_vector_type(4))) float f32x4;

DEVI float bf2f(unsigned short u) {
    union { unsigned int i; float f; } v; v.i = ((unsigned int)u) << 16; return v.f;
}
DEVI float ldf(const void* p, long long i, int f32) {
    return f32 ? ((const float*)p)[i] : bf2f(((const unsigned short*)p)[i]);
}
DEVI unsigned short f2bfu(float x) {
    __hip_bfloat16 h = __float2bfloat16(x);
    return *reinterpret_cast<unsigned short*>(&h);
}
DEVI short f2bf(float x) { return (short)f2bfu(x); }
DEVI float eluf(float x) { return x > 0.f ? x : __expf(x) - 1.f; }

// ---- flag detection: flags[0]=edge_index is int64, flags[1]=floats are fp32
__global__ __launch_bounds__(64) void detect_k(
    const int* __restrict__ eidx32, const unsigned int* __restrict__ wbits,
    int* __restrict__ flags)
{
    int t = threadIdx.x;
    int odd = eidx32[2 * t + 1];
    unsigned long long bz = __ballot(odd == 0);
    unsigned int w = wbits[t];
    unsigned int ex = (w >> 23) & 0xFF;
    unsigned long long bf = __ballot(ex >= 100 && ex <= 130);
    if (t == 0) {
        flags[0] = (bz == ~0ULL) ? 1 : 0;
        flags[1] = (__popcll(bf) >= 48) ? 1 : 0;
    }
}

// -------------- Kernel 1: node pathway -> qkv_bf16[M,64] --------------------
__global__ __launch_bounds__(256) void node_qkv_k(
    const int* __restrict__ flags,
    const void* __restrict__ evec,
    const void* __restrict__ W1, const void* __restrict__ b1,
    const void* __restrict__ W2, const void* __restrict__ b2,
    const void* __restrict__ W,  const void* __restrict__ b,
    unsigned short* __restrict__ qkvb, int M_)
{
    __shared__ float sW[1024], sW2[64], sb[64], sb2[16], sW1[4], sb1[4];
    int t = threadIdx.x;
    int f32 = flags[1];
    for (int i = t; i < 1024; i += 256) sW[i] = ldf(W, i, f32);
    if (t < 64) { sW2[t] = ldf(W2, t, f32); sb[t] = ldf(b, t, f32); }
    if (t < 16) sb2[t] = ldf(b2, t, f32);
    if (t < 4)  { sW1[t] = ldf(W1, t, f32); sb1[t] = ldf(b1, t, f32); }
    __syncthreads();

    int m = blockIdx.x * 256 + t;
    if (m >= M_) return;

    float x = ldf(evec, m, f32);
    float h1[4];
    #pragma unroll
    for (int j = 0; j < 4; ++j) h1[j] = eluf(fmaf(x, sW1[j], sb1[j]));
    float h2[16];
    #pragma unroll
    for (int k = 0; k < 16; ++k) h2[k] = sb2[k];
    #pragma unroll
    for (int j = 0; j < 4; ++j)
        #pragma unroll
        for (int k = 0; k < 16; ++k) h2[k] = fmaf(h1[j], sW2[j*16 + k], h2[k]);

    uint4* op = (uint4*)(qkvb + (size_t)m * 64);
    for (int g = 0; g < 8; ++g) {
        float v[8];
        #pragma unroll
        for (int j = 0; j < 8; ++j) {
            int c = g * 8 + j;
            float a = sb[c];
            #pragma unroll
            for (int k = 0; k < 16; ++k) a = fmaf(h2[k], sW[k*64 + c], a);
            v[j] = a;
        }
        uint4 pk;
        pk.x = (unsigned)f2bfu(v[0]) | ((unsigned)f2bfu(v[1]) << 16);
        pk.y = (unsigned)f2bfu(v[2]) | ((unsigned)f2bfu(v[3]) << 16);
        pk.z = (unsigned)f2bfu(v[4]) | ((unsigned)f2bfu(v[5]) << 16);
        pk.w = (unsigned)f2bfu(v[6]) | ((unsigned)f2bfu(v[7]) << 16);
        op[g] = pk;
    }
}

// --- Kernel 2: histogram of dst (4 edges/thread) + per-edge rank output -----
__global__ __launch_bounds__(256) void hist_k(
    const int* __restrict__ flags, const int* __restrict__ eidx32,
    int* __restrict__ counts, int* __restrict__ rank, int NE_)
{
    int e0 = (blockIdx.x * 256 + threadIdx.x) * 4;
    if (e0 >= NE_) return;
    int i64 = flags[0];
    if (e0 + 3 < NE_) {
        int d[4];
        if (i64) {
            long long w = 2LL * (NE_ + (long long)e0);
            int4 a = *(const int4*)(eidx32 + w);
            int4 b = *(const int4*)(eidx32 + w + 4);
            d[0] = a.x; d[1] = a.z; d[2] = b.x; d[3] = b.z;
        } else {
            #pragma unroll
            for (int i = 0; i < 4; ++i) d[i] = eidx32[(long long)NE_ + e0 + i];
        }
        int r[4];
        #pragma unroll
        for (int i = 0; i < 4; ++i) r[i] = atomicAdd(&counts[d[i]], 1);
        *(int4*)(rank + e0) = make_int4(r[0], r[1], r[2], r[3]);
    } else {
        for (int e = e0; e < NE_; ++e) {
            int dst = i64 ? eidx32[2LL * (NE_ + (long long)e)]
                          : eidx32[(long long)NE_ + e];
            rank[e] = atomicAdd(&counts[dst], 1);
        }
    }
}

// ---------------- Kernel 3a: per-1024-tile block sums ----------------
__global__ __launch_bounds__(256) void scan_a_k(
    const int* __restrict__ counts, int* __restrict__ bsum, int M_)
{
    __shared__ int s[256];
    int t = threadIdx.x;
    int g4 = blockIdx.x * 256 + t;
    int i0 = g4 * 4;
    int v = 0;
    if (i0 + 3 < M_) {
        int4 c = ((const int4*)counts)[g4];
        v = c.x + c.y + c.z + c.w;
    } else {
        for (int k = 0; k < 4 && i0 + k < M_; ++k) v += counts[i0 + k];
    }
    s[t] = v; __syncthreads();
    for (int off = 128; off > 0; off >>= 1) {
        if (t < off) s[t] += s[t + off];
        __syncthreads();
    }
    if (t == 0) bsum[blockIdx.x] = s[0];
}

// ---------------- Kernel 3b: scan block sums (nb <= 256) ----------------
__global__ __launch_bounds__(256) void scan_b_k(
    const int* __restrict__ bsum, int* __restrict__ bexcl, int nb,
    int* __restrict__ offsets, int M_, int NE_)
{
    __shared__ int s[256];
    int t = threadIdx.x;
    int mine = (t < nb) ? bsum[t] : 0;
    s[t] = mine; __syncthreads();
    for (int off = 1; off < 256; off <<= 1) {
        int v = (t >= off) ? s[t - off] : 0;
        __syncthreads();
        s[t] += v;
        __syncthreads();
    }
    if (t < nb) bexcl[t] = s[t] - mine;
    if (t == 0) offsets[M_] = NE_;
}

// ---------------- Kernel 3c: final offsets ----------------
__global__ __launch_bounds__(256) void scan_c_k(
    const int* __restrict__ counts, const int* __restrict__ bexcl,
    int* __restrict__ offsets, int M_)
{
    __shared__ int s[256];
    int t = threadIdx.x;
    int g4 = blockIdx.x * 256 + t;
    int i0 = g4 * 4;
    int c0 = 0, c1 = 0, c2 = 0, c3 = 0;
    if (i0 + 3 < M_) {
        int4 c = ((const int4*)counts)[g4];
        c0 = c.x; c1 = c.y; c2 = c.z; c3 = c.w;
    } else {
        if (i0 + 0 < M_) c0 = counts[i0 + 0];
        if (i0 + 1 < M_) c1 = counts[i0 + 1];
        if (i0 + 2 < M_) c2 = counts[i0 + 2];
        if (i0 + 3 < M_) c3 = counts[i0 + 3];
    }
    int tsum = c0 + c1 + c2 + c3;
    s[t] = tsum; __syncthreads();
    for (int off = 1; off < 256; off <<= 1) {
        int v = (t >= off) ? s[t - off] : 0;
        __syncthreads();
        s[t] += v;
        __syncthreads();
    }
    int run = bexcl[blockIdx.x] + s[t] - tsum;
    if (i0 + 0 < M_) { offsets[i0+0] = run; run += c0; }
    if (i0 + 1 < M_) { offsets[i0+1] = run; run += c1; }
    if (i0 + 2 < M_) { offsets[i0+2] = run; run += c2; }
    if (i0 + 3 < M_) { offsets[i0+3] = run; run += c3; }
}

// --- Kernel 4: scatter records {src, dst, efeat(4xbf16)}; atomic-free -------
__global__ __launch_bounds__(256) void scatter_k(
    const int* __restrict__ flags, const int* __restrict__ eidx32,
    const void* __restrict__ efeat,
    const int* __restrict__ offsets, const int* __restrict__ rank,
    int4* __restrict__ sorted, int NE_)
{
    int e = blockIdx.x * 256 + threadIdx.x;
    if (e >= NE_) return;
    int i64 = flags[0];
    int f32 = flags[1];
    int src, dst;
    if (i64) { src = eidx32[2LL * e]; dst = eidx32[2LL * (NE_ + (long long)e)]; }
    else     { src = eidx32[e];       dst = eidx32[(long long)NE_ + e]; }

    unsigned int ef01, ef23;
    if (f32) {
        const float4 f = ((const float4*)efeat)[e];
        ef01 = (unsigned)f2bfu(f.x) | ((unsigned)f2bfu(f.y) << 16);
        ef23 = (unsigned)f2bfu(f.z) | ((unsigned)f2bfu(f.w) << 16);
    } else {
        const uint2 u = ((const uint2*)efeat)[e];
        ef01 = u.x; ef23 = u.y;
    }

    int pos = offsets[dst] + rank[e];
    sorted[pos] = make_int4(src, dst, (int)ef01, (int)ef23);
}

// ----- Kernel 5: scores via MFMA + LDS transpose; XCD-contiguous regions ----
__global__ __launch_bounds__(256) void score_k(
    const int* __restrict__ flags, const int4* __restrict__ sorted,
    const void* __restrict__ W2, const void* __restrict__ b2,
    const void* __restrict__ W,  const void* __restrict__ b,
    const unsigned short* __restrict__ qkvb, float* __restrict__ score, int NE_)
{
    __shared__ float sW2[64], sb2[16];
    __shared__ float sE[4][16 * 68];
    int t = threadIdx.x;
    int f32 = flags[1];
    if (t < 64) sW2[t] = ldf(W2, t, f32);
    if (t < 16) sb2[t] = ldf(b2, t, f32);
    __syncthreads();

    int wv   = t >> 6;
    int lane = t & 63;
    int col  = lane & 15;
    int quad = lane >> 4;
    float* myE = &sE[wv][0];

    bf16x8 bfrag[4];
    float  bb[4];
    #pragma unroll
    for (int h = 0; h < 4; ++h) {
        #pragma unroll
        for (int jj = 0; jj < 8; ++jj) {
            int k = quad * 8 + jj;
            float wv_ = (k < 16) ? ldf(W, k * 64 + h * 16 + col, f32) : 0.f;
            bfrag[h][jj] = f2bf(wv_);
        }
        bb[h] = ldf(b, h * 16 + col, f32);
    }

    int j2 = lane >> 2, h2 = lane & 3;

    long long tiles = ((long long)NE_ + 15) >> 4;
    // XCD-contiguous regions: blocks with blockIdx%8==r serve region r
    long long Tr   = (tiles + 7) >> 3;
    int       xcd  = blockIdx.x & 7;
    int       lb   = blockIdx.x >> 3;
    long long tEnd = (long long)(xcd + 1) * Tr; if (tEnd > tiles) tEnd = tiles;
    long long stride = (long long)(gridDim.x >> 3) * 4;

    long long tile = (long long)xcd * Tr + (long long)lb * 4 + wv;
    int4 rec = make_int4(0, 0, 0, 0);
    if (tile < tEnd) {
        int jA = (int)(tile << 4) + col;
        if (jA < NE_) rec = sorted[jA];
    }

    while (tile < tEnd) {
        long long tnext = tile + stride;
        int4 recn = make_int4(0, 0, 0, 0);
        if (tnext < tEnd) {
            int jB = (int)(tnext << 4) + col;
            if (jB < NE_) recn = sorted[jB];
        }

        int base = (int)(tile << 4);
        float ef0 = bf2f((unsigned short)((unsigned)rec.z & 0xffff));
        float ef1 = bf2f((unsigned short)((unsigned)rec.z >> 16));
        float ef2 = bf2f((unsigned short)((unsigned)rec.w & 0xffff));
        float ef3 = bf2f((unsigned short)((unsigned)rec.w >> 16));

        bf16x8 afrag;
        #pragma unroll
        for (int jj = 0; jj < 8; ++jj) {
            int k = quad * 8 + jj;
            float v = 0.f;
            if (k < 16) {
                v = eluf(fmaf(ef0, sW2[k],
                        fmaf(ef1, sW2[16 + k],
                        fmaf(ef2, sW2[32 + k],
                        fmaf(ef3, sW2[48 + k], sb2[k])))));
            }
            afrag[jj] = f2bf(v);
        }

        f32x4 acc[4];
        #pragma unroll
        for (int h = 0; h < 4; ++h) {
            acc[h] = (f32x4){0.f, 0.f, 0.f, 0.f};
            acc[h] = __builtin_amdgcn_mfma_f32_16x16x32_bf16(afrag, bfrag[h], acc[h], 0, 0, 0);
        }

        #pragma unroll
        for (int h = 0; h < 4; ++h)
            #pragma unroll
            for (int r = 0; r < 4; ++r)
                myE[(quad * 4 + r) * 68 + h * 16 + col] = acc[h][r] + bb[h];

        asm volatile("s_waitcnt lgkmcnt(0)" ::: "memory");

        int srcj = __shfl(rec.x, j2, 64);
        int dstj = __shfl(rec.y, j2, 64);

        const uint4* sp = (const uint4*)(qkvb + (size_t)srcj * 64 + h2 * 16);
        const uint4* dp = (const uint4*)(qkvb + (size_t)dstj * 64 + h2 * 16);
        uint4 sA = sp[0], sB = sp[1], dA = dp[0], dB = dp[1];

        const float4* ep = (const float4*)(myE + j2 * 68 + h2 * 16);
        float4 e0 = ep[0], e1 = ep[1], e2 = ep[2], e3 = ep[3];
        float E[16] = {e0.x,e0.y,e0.z,e0.w, e1.x,e1.y,e1.z,e1.w,
                       e2.x,e2.y,e2.z,e2.w, e3.x,e3.y,e3.z,e3.w};

        unsigned int su[8] = {sA.x,sA.y,sA.z,sA.w, sB.x,sB.y,sB.z,sB.w};
        unsigned int du[8] = {dA.x,dA.y,dA.z,dA.w, dB.x,dB.y,dB.z,dB.w};

        float sc = 0.f;
        #pragma unroll
        for (int i = 0; i < 8; ++i) {
            float s0 = bf2f((unsigned short)(su[i] & 0xffff));
            float s1 = bf2f((unsigned short)(su[i] >> 16));
            float d0 = bf2f((unsigned short)(du[i] & 0xffff));
            float d1 = bf2f((unsigned short)(du[i] >> 16));
            sc = fmaf(s0 * d0, E[2*i],   sc);
            sc = fmaf(s1 * d1, E[2*i+1], sc);
        }
        sc *= 0.25f;
        sc = fminf(fmaxf(sc, -5.f), 5.f);
        float s = __expf(sc);

        int jW = base + j2;
        if (jW < NE_) score[(size_t)jW * 4 + h2] = s;

        rec = recn;
        tile = tnext;
    }
}

// --- Kernel 6: accumulate, 8 lanes/dst (h x half-row), 4-deep pipeline ------
__global__ __launch_bounds__(256) void accum_out_k(
    const int* __restrict__ flags,
    const int* __restrict__ offsets, const int4* __restrict__ sorted,
    const float* __restrict__ score, const unsigned short* __restrict__ qkvb,
    const void* __restrict__ Wout, const void* __restrict__ bout,
    const void* __restrict__ Wout1, const void* __restrict__ bout1,
    void* __restrict__ out, int M_)
{
    __shared__ float sWo[1024], sbo[16], sWo1[16];
    __shared__ float sbo1;
    int t = threadIdx.x;
    int f32 = flags[1];
    for (int i = t; i < 1024; i += 256) sWo[i] = ldf(Wout, i, f32);
    if (t < 16) { sbo[t] = ldf(bout, t, f32); sWo1[t] = ldf(Wout1, t, f32); }
    if (t == 0) sbo1 = ldf(bout1, 0, f32);
    __syncthreads();

    int gid = blockIdx.x * 256 + t;
    int m = gid >> 3;
    if (m >= M_) return;
    int sub  = gid & 7;            // (h, half)
    int h    = sub >> 1;
    int off16 = h * 16 + (sub & 1) * 8;   // this lane's 8 bf16 of the row

    int beg = offsets[m], end = offsets[m + 1];

    float acc[8];
    #pragma unroll
    for (int d = 0; d < 8; ++d) acc[d] = 0.f;
    float z = 0.f;

    int j = beg;
    for (; j + 4 <= end; j += 4) {
        int s4[4];
        float sc4[4];
        #pragma unroll
        for (int u = 0; u < 4; ++u) {
            s4[u]  = sorted[j + u].x;
            sc4[u] = score[(size_t)(j + u) * 4 + h];
        }
        uint4 q[4];
        #pragma unroll
        for (int u = 0; u < 4; ++u)
            q[u] = *(const uint4*)(qkvb + (size_t)s4[u] * 64 + off16);
        #pragma unroll
        for (int u = 0; u < 4; ++u) {
            float s = sc4[u];
            z += s;
            unsigned int qq[4] = {q[u].x, q[u].y, q[u].z, q[u].w};
            #pragma unroll
            for (int i = 0; i < 4; ++i) {
                acc[2*i]   = fmaf(bf2f((unsigned short)(qq[i] & 0xffff)), s, acc[2*i]);
                acc[2*i+1] = fmaf(bf2f((unsigned short)(qq[i] >> 16)),    s, acc[2*i+1]);
            }
        }
    }
    for (; j < end; ++j) {
        int s0 = sorted[j].x;
        float s = score[(size_t)j * 4 + h];
        uint4 q = *(const uint4*)(qkvb + (size_t)s0 * 64 + off16);
        z += s;
        unsigned int qq[4] = {q.x, q.y, q.z, q.w};
        #pragma unroll
        for (int i = 0; i < 4; ++i) {
            acc[2*i]   = fmaf(bf2f((unsigned short)(qq[i] & 0xffff)), s, acc[2*i]);
            acc[2*i+1] = fmaf(bf2f((unsigned short)(qq[i] >> 16)),    s, acc[2*i+1]);
        }
    }

    float zinv = 1.f / (z + 1e-6f);

    float p[16];
    #pragma unroll
    for (int jj = 0; jj < 16; ++jj) p[jj] = 0.f;
    #pragma unroll
    for (int d = 0; d < 8; ++d) {
        float hv = acc[d] * zinv;
        int c = off16 + d;
        #pragma unroll
        for (int jj = 0; jj < 16; ++jj) p[jj] = fmaf(hv, sWo[c * 16 + jj], p[jj]);
    }
    #pragma unroll
    for (int jj = 0; jj < 16; ++jj) {
        p[jj] += __shfl_xor(p[jj], 1, 64);
        p[jj] += __shfl_xor(p[jj], 2, 64);
        p[jj] += __shfl_xor(p[jj], 4, 64);
    }
    if (sub == 0) {
        float o = sbo1;
        #pragma unroll
        for (int jj = 0; jj < 16; ++jj) o = fmaf(eluf(p[jj] + sbo[jj]), sWo1[jj], o);
        if (f32) ((float*)out)[m] = o;
        else     ((__hip_bfloat16*)out)[m] = __float2bfloat16(o);
    }
}

extern "C" void kernel_launch(void* const* d_in, const int* in_sizes, int n_in,
                              void* d_out, int out_size, void* d_ws, size_t ws_size,
                              hipStream_t stream)
{
    const int*  eidx  = (const int*)d_in[1];
    const void* efeat = d_in[2];
    const void* evec  = d_in[3];
    const void* W1 = d_in[4],  *b1 = d_in[5];
    const void* W2 = d_in[6],  *b2 = d_in[7];
    const void* W  = d_in[8],  *b  = d_in[9];
    const void* Wout = d_in[10], *bout = d_in[11];
    const void* Wout1 = d_in[12], *bout1 = d_in[13];

    const int M_  = in_sizes[3];       // 150000
    const int NE_ = in_sizes[1] / 2;   // 1500000
    const int nb  = (M_ + 1023) / 1024;

    // workspace layout (16B aligned); ~75 MB (<79.2 MB proven available)
    char* wp = (char*)d_ws;
    int*            flags   = (int*)wp;                 wp += 16;
    unsigned short* qkvb    = (unsigned short*)wp;      wp += (size_t)M_ * 64 * 2;
    int*            counts  = (int*)wp;                 wp += (size_t)M_ * 4;
    int*            bsum    = (int*)wp;                 wp += 2048 * 4;
    int*            bexcl   = (int*)wp;                 wp += 2048 * 4;
    int*            offsets = (int*)wp;                 wp += ((size_t)M_ + 4) * 4;
    int*            rank    = (int*)wp;                 wp += (size_t)NE_ * 4;
    wp = (char*)(((uintptr_t)wp + 15) & ~(uintptr_t)15);
    int4*           sorted  = (int4*)wp;                wp += (size_t)NE_ * 16;
    float*          scoreB  = (float*)wp;               // NE*4 fp32 = 24 MB

    detect_k<<<1, 64, 0, stream>>>(eidx, (const unsigned int*)W, flags);
    (void)hipMemsetAsync(counts, 0, (size_t)M_ * 4, stream);

    node_qkv_k<<<(M_ + 255) / 256, 256, 0, stream>>>(
        flags, evec, W1, b1, W2, b2, W, b, qkvb, M_);

    int q4 = (NE_ + 3) / 4;
    hist_k<<<(q4 + 255) / 256, 256, 0, stream>>>(flags, eidx, counts, rank, NE_);
    scan_a_k<<<nb, 256, 0, stream>>>(counts, bsum, M_);
    scan_b_k<<<1, 256, 0, stream>>>(bsum, bexcl, nb, offsets, M_, NE_);
    scan_c_k<<<nb, 256, 0, stream>>>(counts, bexcl, offsets, M_);
    scatter_k<<<(NE_ + 255) / 256, 256, 0, stream>>>(
        flags, eidx, efeat, offsets, rank, sorted, NE_);

    long long tiles = ((long long)NE_ + 15) / 16;
    int sblocks = (int)((tiles + 3) / 4);
    sblocks = ((sblocks + 7) / 8) * 8;       // multiple of 8 for XCD regions
    if (sblocks > 12288) sblocks = 12288;
    score_k<<<sblocks, 256, 0, stream>>>(
        flags, sorted, W2, b2, W, b, qkvb, scoreB, NE_);

    long long tot = (long long)M_ * 8;       // 8 lanes per dst
    accum_out_k<<<(int)((tot + 255) / 256), 256, 0, stream>>>(
        flags, offsets, sorted, scoreB, qkvb,
        Wout, bout, Wout1, bout1, d_out, M_);
}

// Round 14
// 360.284 us; speedup vs baseline: 1.0241x; 1.0209x over previous
//
#include <hip/hip_runtime.h>
#include <hip/hip_bf16.h>
#include <cstdint>

#define DEVI __device__ __forceinline__

typedef __attribute__((ext_vector_type(8))) short bf16x8;
typedef __attribute__((ext_vector_type(4))) float f32x4;

DEVI float bf2f(unsigned short u) {
    union { unsigned int i; float f; } v; v.i = ((unsigned int)u) << 16; return v.f;
}
DEVI float ldf(const void* p, long long i, int f32) {
    return f32 ? ((const float*)p)[i] : bf2f(((const unsigned short*)p)[i]);
}
DEVI unsigned short f2bfu(float x) {
    __hip_bfloat16 h = __float2bfloat16(x);
    return *reinterpret_cast<unsigned short*>(&h);
}
DEVI short f2bf(float x) { return (short)f2bfu(x); }
DEVI float eluf(float x) { return x > 0.f ? x : __expf(x) - 1.f; }

// ---- flag detection: flags[0]=edge_index is int64, flags[1]=floats are fp32
__global__ __launch_bounds__(64) void detect_k(
    const int* __restrict__ eidx32, const unsigned int* __restrict__ wbits,
    int* __restrict__ flags)
{
    int t = threadIdx.x;
    int odd = eidx32[2 * t + 1];
    unsigned long long bz = __ballot(odd == 0);
    unsigned int w = wbits[t];
    unsigned int ex = (w >> 23) & 0xFF;
    unsigned long long bf = __ballot(ex >= 100 && ex <= 130);
    if (t == 0) {
        flags[0] = (bz == ~0ULL) ? 1 : 0;
        flags[1] = (__popcll(bf) >= 48) ? 1 : 0;
    }
}

// -------------- Kernel 1: node pathway -> qkv_bf16[M,64] --------------------
__global__ __launch_bounds__(256) void node_qkv_k(
    const int* __restrict__ flags,
    const void* __restrict__ evec,
    const void* __restrict__ W1, const void* __restrict__ b1,
    const void* __restrict__ W2, const void* __restrict__ b2,
    const void* __restrict__ W,  const void* __restrict__ b,
    unsigned short* __restrict__ qkvb, int M_)
{
    __shared__ float sW[1024], sW2[64], sb[64], sb2[16], sW1[4], sb1[4];
    int t = threadIdx.x;
    int f32 = flags[1];
    for (int i = t; i < 1024; i += 256) sW[i] = ldf(W, i, f32);
    if (t < 64) { sW2[t] = ldf(W2, t, f32); sb[t] = ldf(b, t, f32); }
    if (t < 16) sb2[t] = ldf(b2, t, f32);
    if (t < 4)  { sW1[t] = ldf(W1, t, f32); sb1[t] = ldf(b1, t, f32); }
    __syncthreads();

    int m = blockIdx.x * 256 + t;
    if (m >= M_) return;

    float x = ldf(evec, m, f32);
    float h1[4];
    #pragma unroll
    for (int j = 0; j < 4; ++j) h1[j] = eluf(fmaf(x, sW1[j], sb1[j]));
    float h2[16];
    #pragma unroll
    for (int k = 0; k < 16; ++k) h2[k] = sb2[k];
    #pragma unroll
    for (int j = 0; j < 4; ++j)
        #pragma unroll
        for (int k = 0; k < 16; ++k) h2[k] = fmaf(h1[j], sW2[j*16 + k], h2[k]);

    uint4* op = (uint4*)(qkvb + (size_t)m * 64);
    for (int g = 0; g < 8; ++g) {
        float v[8];
        #pragma unroll
        for (int j = 0; j < 8; ++j) {
            int c = g * 8 + j;
            float a = sb[c];
            #pragma unroll
            for (int k = 0; k < 16; ++k) a = fmaf(h2[k], sW[k*64 + c], a);
            v[j] = a;
        }
        uint4 pk;
        pk.x = (unsigned)f2bfu(v[0]) | ((unsigned)f2bfu(v[1]) << 16);
        pk.y = (unsigned)f2bfu(v[2]) | ((unsigned)f2bfu(v[3]) << 16);
        pk.z = (unsigned)f2bfu(v[4]) | ((unsigned)f2bfu(v[5]) << 16);
        pk.w = (unsigned)f2bfu(v[6]) | ((unsigned)f2bfu(v[7]) << 16);
        op[g] = pk;
    }
}

// --- Kernel 2: histogram of dst (4 edges/thread) + per-edge rank output -----
__global__ __launch_bounds__(256) void hist_k(
    const int* __restrict__ flags, const int* __restrict__ eidx32,
    int* __restrict__ counts, int* __restrict__ rank, int NE_)
{
    int e0 = (blockIdx.x * 256 + threadIdx.x) * 4;
    if (e0 >= NE_) return;
    int i64 = flags[0];
    if (e0 + 3 < NE_) {
        int d[4];
        if (i64) {
            long long w = 2LL * (NE_ + (long long)e0);
            int4 a = *(const int4*)(eidx32 + w);
            int4 b = *(const int4*)(eidx32 + w + 4);
            d[0] = a.x; d[1] = a.z; d[2] = b.x; d[3] = b.z;
        } else {
            #pragma unroll
            for (int i = 0; i < 4; ++i) d[i] = eidx32[(long long)NE_ + e0 + i];
        }
        int r[4];
        #pragma unroll
        for (int i = 0; i < 4; ++i) r[i] = atomicAdd(&counts[d[i]], 1);
        *(int4*)(rank + e0) = make_int4(r[0], r[1], r[2], r[3]);
    } else {
        for (int e = e0; e < NE_; ++e) {
            int dst = i64 ? eidx32[2LL * (NE_ + (long long)e)]
                          : eidx32[(long long)NE_ + e];
            rank[e] = atomicAdd(&counts[dst], 1);
        }
    }
}

// ---------------- Kernel 3a: per-1024-tile block sums ----------------
__global__ __launch_bounds__(256) void scan_a_k(
    const int* __restrict__ counts, int* __restrict__ bsum, int M_)
{
    __shared__ int s[256];
    int t = threadIdx.x;
    int g4 = blockIdx.x * 256 + t;
    int i0 = g4 * 4;
    int v = 0;
    if (i0 + 3 < M_) {
        int4 c = ((const int4*)counts)[g4];
        v = c.x + c.y + c.z + c.w;
    } else {
        for (int k = 0; k < 4 && i0 + k < M_; ++k) v += counts[i0 + k];
    }
    s[t] = v; __syncthreads();
    for (int off = 128; off > 0; off >>= 1) {
        if (t < off) s[t] += s[t + off];
        __syncthreads();
    }
    if (t == 0) bsum[blockIdx.x] = s[0];
}

// ---------------- Kernel 3b: scan block sums (nb <= 256) ----------------
__global__ __launch_bounds__(256) void scan_b_k(
    const int* __restrict__ bsum, int* __restrict__ bexcl, int nb,
    int* __restrict__ offsets, int M_, int NE_)
{
    __shared__ int s[256];
    int t = threadIdx.x;
    int mine = (t < nb) ? bsum[t] : 0;
    s[t] = mine; __syncthreads();
    for (int off = 1; off < 256; off <<= 1) {
        int v = (t >= off) ? s[t - off] : 0;
        __syncthreads();
        s[t] += v;
        __syncthreads();
    }
    if (t < nb) bexcl[t] = s[t] - mine;
    if (t == 0) offsets[M_] = NE_;
}

// ---------------- Kernel 3c: final offsets ----------------
__global__ __launch_bounds__(256) void scan_c_k(
    const int* __restrict__ counts, const int* __restrict__ bexcl,
    int* __restrict__ offsets, int M_)
{
    __shared__ int s[256];
    int t = threadIdx.x;
    int g4 = blockIdx.x * 256 + t;
    int i0 = g4 * 4;
    int c0 = 0, c1 = 0, c2 = 0, c3 = 0;
    if (i0 + 3 < M_) {
        int4 c = ((const int4*)counts)[g4];
        c0 = c.x; c1 = c.y; c2 = c.z; c3 = c.w;
    } else {
        if (i0 + 0 < M_) c0 = counts[i0 + 0];
        if (i0 + 1 < M_) c1 = counts[i0 + 1];
        if (i0 + 2 < M_) c2 = counts[i0 + 2];
        if (i0 + 3 < M_) c3 = counts[i0 + 3];
    }
    int tsum = c0 + c1 + c2 + c3;
    s[t] = tsum; __syncthreads();
    for (int off = 1; off < 256; off <<= 1) {
        int v = (t >= off) ? s[t - off] : 0;
        __syncthreads();
        s[t] += v;
        __syncthreads();
    }
    int run = bexcl[blockIdx.x] + s[t] - tsum;
    if (i0 + 0 < M_) { offsets[i0+0] = run; run += c0; }
    if (i0 + 1 < M_) { offsets[i0+1] = run; run += c1; }
    if (i0 + 2 < M_) { offsets[i0+2] = run; run += c2; }
    if (i0 + 3 < M_) { offsets[i0+3] = run; run += c3; }
}

// --- Kernel 4: scatter records {src, dst, efeat(4xbf16)}; atomic-free -------
__global__ __launch_bounds__(256) void scatter_k(
    const int* __restrict__ flags, const int* __restrict__ eidx32,
    const void* __restrict__ efeat,
    const int* __restrict__ offsets, const int* __restrict__ rank,
    int4* __restrict__ sorted, int NE_)
{
    int e = blockIdx.x * 256 + threadIdx.x;
    if (e >= NE_) return;
    int i64 = flags[0];
    int f32 = flags[1];
    int src, dst;
    if (i64) { src = eidx32[2LL * e]; dst = eidx32[2LL * (NE_ + (long long)e)]; }
    else     { src = eidx32[e];       dst = eidx32[(long long)NE_ + e]; }

    unsigned int ef01, ef23;
    if (f32) {
        const float4 f = ((const float4*)efeat)[e];
        ef01 = (unsigned)f2bfu(f.x) | ((unsigned)f2bfu(f.y) << 16);
        ef23 = (unsigned)f2bfu(f.z) | ((unsigned)f2bfu(f.w) << 16);
    } else {
        const uint2 u = ((const uint2*)efeat)[e];
        ef01 = u.x; ef23 = u.y;
    }

    int pos = offsets[dst] + rank[e];
    sorted[pos] = make_int4(src, dst, (int)ef01, (int)ef23);
}

// ----- Kernel 5: scores via MFMA + LDS transpose; XCD-contiguous regions ----
__global__ __launch_bounds__(256) void score_k(
    const int* __restrict__ flags, const int4* __restrict__ sorted,
    const void* __restrict__ W2, const void* __restrict__ b2,
    const void* __restrict__ W,  const void* __restrict__ b,
    const unsigned short* __restrict__ qkvb, float* __restrict__ score, int NE_)
{
    __shared__ float sW2[64], sb2[16];
    __shared__ float sE[4][16 * 68];
    int t = threadIdx.x;
    int f32 = flags[1];
    if (t < 64) sW2[t] = ldf(W2, t, f32);
    if (t < 16) sb2[t] = ldf(b2, t, f32);
    __syncthreads();

    int wv   = t >> 6;
    int lane = t & 63;
    int col  = lane & 15;
    int quad = lane >> 4;
    float* myE = &sE[wv][0];

    bf16x8 bfrag[4];
    float  bb[4];
    #pragma unroll
    for (int h = 0; h < 4; ++h) {
        #pragma unroll
        for (int jj = 0; jj < 8; ++jj) {
            int k = quad * 8 + jj;
            float wv_ = (k < 16) ? ldf(W, k * 64 + h * 16 + col, f32) : 0.f;
            bfrag[h][jj] = f2bf(wv_);
        }
        bb[h] = ldf(b, h * 16 + col, f32);
    }

    int j2 = lane >> 2, h2 = lane & 3;

    long long tiles = ((long long)NE_ + 15) >> 4;
    long long Tr   = (tiles + 7) >> 3;
    int       xcd  = blockIdx.x & 7;
    int       lb   = blockIdx.x >> 3;
    long long tEnd = (long long)(xcd + 1) * Tr; if (tEnd > tiles) tEnd = tiles;
    long long stride = (long long)(gridDim.x >> 3) * 4;

    long long tile = (long long)xcd * Tr + (long long)lb * 4 + wv;
    int4 rec = make_int4(0, 0, 0, 0);
    if (tile < tEnd) {
        int jA = (int)(tile << 4) + col;
        if (jA < NE_) rec = sorted[jA];
    }

    while (tile < tEnd) {
        long long tnext = tile + stride;
        int4 recn = make_int4(0, 0, 0, 0);
        if (tnext < tEnd) {
            int jB = (int)(tnext << 4) + col;
            if (jB < NE_) recn = sorted[jB];
        }

        int base = (int)(tile << 4);
        float ef0 = bf2f((unsigned short)((unsigned)rec.z & 0xffff));
        float ef1 = bf2f((unsigned short)((unsigned)rec.z >> 16));
        float ef2 = bf2f((unsigned short)((unsigned)rec.w & 0xffff));
        float ef3 = bf2f((unsigned short)((unsigned)rec.w >> 16));

        bf16x8 afrag;
        #pragma unroll
        for (int jj = 0; jj < 8; ++jj) {
            int k = quad * 8 + jj;
            float v = 0.f;
            if (k < 16) {
                v = eluf(fmaf(ef0, sW2[k],
                        fmaf(ef1, sW2[16 + k],
                        fmaf(ef2, sW2[32 + k],
                        fmaf(ef3, sW2[48 + k], sb2[k])))));
            }
            afrag[jj] = f2bf(v);
        }

        f32x4 acc[4];
        #pragma unroll
        for (int h = 0; h < 4; ++h) {
            acc[h] = (f32x4){0.f, 0.f, 0.f, 0.f};
            acc[h] = __builtin_amdgcn_mfma_f32_16x16x32_bf16(afrag, bfrag[h], acc[h], 0, 0, 0);
        }

        #pragma unroll
        for (int h = 0; h < 4; ++h)
            #pragma unroll
            for (int r = 0; r < 4; ++r)
                myE[(quad * 4 + r) * 68 + h * 16 + col] = acc[h][r] + bb[h];

        asm volatile("s_waitcnt lgkmcnt(0)" ::: "memory");

        int srcj = __shfl(rec.x, j2, 64);
        int dstj = __shfl(rec.y, j2, 64);

        const uint4* sp = (const uint4*)(qkvb + (size_t)srcj * 64 + h2 * 16);
        const uint4* dp = (const uint4*)(qkvb + (size_t)dstj * 64 + h2 * 16);
        uint4 sA = sp[0], sB = sp[1], dA = dp[0], dB = dp[1];

        const float4* ep = (const float4*)(myE + j2 * 68 + h2 * 16);
        float4 e0 = ep[0], e1 = ep[1], e2 = ep[2], e3 = ep[3];
        float E[16] = {e0.x,e0.y,e0.z,e0.w, e1.x,e1.y,e1.z,e1.w,
                       e2.x,e2.y,e2.z,e2.w, e3.x,e3.y,e3.z,e3.w};

        unsigned int su[8] = {sA.x,sA.y,sA.z,sA.w, sB.x,sB.y,sB.z,sB.w};
        unsigned int du[8] = {dA.x,dA.y,dA.z,dA.w, dB.x,dB.y,dB.z,dB.w};

        float sc = 0.f;
        #pragma unroll
        for (int i = 0; i < 8; ++i) {
            float s0 = bf2f((unsigned short)(su[i] & 0xffff));
            float s1 = bf2f((unsigned short)(su[i] >> 16));
            float d0 = bf2f((unsigned short)(du[i] & 0xffff));
            float d1 = bf2f((unsigned short)(du[i] >> 16));
            sc = fmaf(s0 * d0, E[2*i],   sc);
            sc = fmaf(s1 * d1, E[2*i+1], sc);
        }
        sc *= 0.25f;
        sc = fminf(fmaxf(sc, -5.f), 5.f);
        float s = __expf(sc);

        int jW = base + j2;
        if (jW < NE_) score[(size_t)jW * 4 + h2] = s;

        rec = recn;
        tile = tnext;
    }
}

// --- Kernel 6: per-(dst,head) accumulate (4-deep pipeline) + output MLP -----
__global__ __launch_bounds__(256) void accum_out_k(
    const int* __restrict__ flags,
    const int* __restrict__ offsets, const int4* __restrict__ sorted,
    const float* __restrict__ score, const unsigned short* __restrict__ qkvb,
    const void* __restrict__ Wout, const void* __restrict__ bout,
    const void* __restrict__ Wout1, const void* __restrict__ bout1,
    void* __restrict__ out, int M_)
{
    __shared__ float sWo[1024], sbo[16], sWo1[16];
    __shared__ float sbo1;
    int t = threadIdx.x;
    int f32 = flags[1];
    for (int i = t; i < 1024; i += 256) sWo[i] = ldf(Wout, i, f32);
    if (t < 16) { sbo[t] = ldf(bout, t, f32); sWo1[t] = ldf(Wout1, t, f32); }
    if (t == 0) sbo1 = ldf(bout1, 0, f32);
    __syncthreads();

    int gid = blockIdx.x * 256 + t;
    int m = gid >> 2;
    if (m >= M_) return;
    int h  = gid & 3;
    int hb = h * 16;

    int beg = offsets[m], end = offsets[m + 1];

    float acc[16];
    #pragma unroll
    for (int d = 0; d < 16; ++d) acc[d] = 0.f;
    float z = 0.f;

    int j = beg;
    for (; j + 4 <= end; j += 4) {
        int s4[4];
        float sc4[4];
        #pragma unroll
        for (int u = 0; u < 4; ++u) {
            s4[u]  = sorted[j + u].x;
            sc4[u] = score[(size_t)(j + u) * 4 + h];
        }
        uint4 qa[4], qb[4];
        #pragma unroll
        for (int u = 0; u < 4; ++u) {
            const uint4* p = (const uint4*)(qkvb + (size_t)s4[u] * 64 + hb);
            qa[u] = p[0]; qb[u] = p[1];
        }
        #pragma unroll
        for (int u = 0; u < 4; ++u) {
            float s = sc4[u];
            z += s;
            unsigned int q[8] = {qa[u].x,qa[u].y,qa[u].z,qa[u].w,
                                 qb[u].x,qb[u].y,qb[u].z,qb[u].w};
            #pragma unroll
            for (int i = 0; i < 8; ++i) {
                acc[2*i]   = fmaf(bf2f((unsigned short)(q[i] & 0xffff)), s, acc[2*i]);
                acc[2*i+1] = fmaf(bf2f((unsigned short)(q[i] >> 16)),    s, acc[2*i+1]);
            }
        }
    }
    for (; j < end; ++j) {
        int s0 = sorted[j].x;
        float sc0 = score[(size_t)j * 4 + h];
        const uint4* p0 = (const uint4*)(qkvb + (size_t)s0 * 64 + hb);
        uint4 a0 = p0[0], a1 = p0[1];
        z += sc0;
        unsigned int q0[8] = {a0.x,a0.y,a0.z,a0.w, a1.x,a1.y,a1.z,a1.w};
        #pragma unroll
        for (int i = 0; i < 8; ++i) {
            acc[2*i]   = fmaf(bf2f((unsigned short)(q0[i] & 0xffff)), sc0, acc[2*i]);
            acc[2*i+1] = fmaf(bf2f((unsigned short)(q0[i] >> 16)),    sc0, acc[2*i+1]);
        }
    }

    float zinv = 1.f / (z + 1e-6f);

    float p[16];
    #pragma unroll
    for (int jj = 0; jj < 16; ++jj) p[jj] = 0.f;
    #pragma unroll
    for (int d = 0; d < 16; ++d) {
        float hv = acc[d] * zinv;
        #pragma unroll
        for (int jj = 0; jj < 16; ++jj) p[jj] = fmaf(hv, sWo[(hb + d) * 16 + jj], p[jj]);
    }
    #pragma unroll
    for (int jj = 0; jj < 16; ++jj) {
        p[jj] += __shfl_xor(p[jj], 1, 64);
        p[jj] += __shfl_xor(p[jj], 2, 64);
    }
    if (h == 0) {
        float o = sbo1;
        #pragma unroll
        for (int jj = 0; jj < 16; ++jj) o = fmaf(eluf(p[jj] + sbo[jj]), sWo1[jj], o);
        if (f32) ((float*)out)[m] = o;
        else     ((__hip_bfloat16*)out)[m] = __float2bfloat16(o);
    }
}

extern "C" void kernel_launch(void* const* d_in, const int* in_sizes, int n_in,
                              void* d_out, int out_size, void* d_ws, size_t ws_size,
                              hipStream_t stream)
{
    const int*  eidx  = (const int*)d_in[1];
    const void* efeat = d_in[2];
    const void* evec  = d_in[3];
    const void* W1 = d_in[4],  *b1 = d_in[5];
    const void* W2 = d_in[6],  *b2 = d_in[7];
    const void* W  = d_in[8],  *b  = d_in[9];
    const void* Wout = d_in[10], *bout = d_in[11];
    const void* Wout1 = d_in[12], *bout1 = d_in[13];

    const int M_  = in_sizes[3];       // 150000
    const int NE_ = in_sizes[1] / 2;   // 1500000
    const int nb  = (M_ + 1023) / 1024;

    // workspace layout (16B aligned); ~75 MB (<79.2 MB proven available)
    char* wp = (char*)d_ws;
    int*            flags   = (int*)wp;                 wp += 16;
    unsigned short* qkvb    = (unsigned short*)wp;      wp += (size_t)M_ * 64 * 2;
    int*            counts  = (int*)wp;                 wp += (size_t)M_ * 4;
    int*            bsum    = (int*)wp;                 wp += 2048 * 4;
    int*            bexcl   = (int*)wp;                 wp += 2048 * 4;
    int*            offsets = (int*)wp;                 wp += ((size_t)M_ + 4) * 4;
    int*            rank    = (int*)wp;                 wp += (size_t)NE_ * 4;
    wp = (char*)(((uintptr_t)wp + 15) & ~(uintptr_t)15);
    int4*           sorted  = (int4*)wp;                wp += (size_t)NE_ * 16;
    float*          scoreB  = (float*)wp;               // NE*4 fp32 = 24 MB

    detect_k<<<1, 64, 0, stream>>>(eidx, (const unsigned int*)W, flags);
    (void)hipMemsetAsync(counts, 0, (size_t)M_ * 4, stream);

    node_qkv_k<<<(M_ + 255) / 256, 256, 0, stream>>>(
        flags, evec, W1, b1, W2, b2, W, b, qkvb, M_);

    int q4 = (NE_ + 3) / 4;
    hist_k<<<(q4 + 255) / 256, 256, 0, stream>>>(flags, eidx, counts, rank, NE_);
    scan_a_k<<<nb, 256, 0, stream>>>(counts, bsum, M_);
    scan_b_k<<<1, 256, 0, stream>>>(bsum, bexcl, nb, offsets, M_, NE_);
    scan_c_k<<<nb, 256, 0, stream>>>(counts, bexcl, offsets, M_);
    scatter_k<<<(NE_ + 255) / 256, 256, 0, stream>>>(
        flags, eidx, efeat, offsets, rank, sorted, NE_);

    long long tiles = ((long long)NE_ + 15) / 16;
    int sblocks = (int)((tiles + 3) / 4);
    sblocks = ((sblocks + 7) / 8) * 8;       // multiple of 8 for XCD regions
    if (sblocks > 12288) sblocks = 12288;
    score_k<<<sblocks, 256, 0, stream>>>(
        flags, sorted, W2, b2, W, b, qkvb, scoreB, NE_);

    long long tot = (long long)M_ * 4;       // 4 lanes per dst (R12 shape)
    accum_out_k<<<(int)((tot + 255) / 256), 256, 0, stream>>>(
        flags, offsets, sorted, scoreB, qkvb,
        Wout, bout, Wout1, bout1, d_out, M_);
}